// Round 14
// baseline (100.693 us; speedup 1.0000x reference)
//
#include <hip/hip_runtime.h>
#include <hip/hip_bf16.h>

#define N 4096
#define F 256
#define P 5
#define EPSV 1e-8f
#define BK 32
#define NSTEP (F / BK)  // 8
#define NTRI 2080       // 64*65/2 upper-triangle 64x64 tiles
#define GRIDSZ 768      // persistent blocks
#define DDEG 12         // polynomial degree for tanh(sc*exp(invT*g))
#define NC (DDEG + 1)   // 13 coefficients per persona

typedef __attribute__((ext_vector_type(8))) short bf16x8;
typedef __attribute__((ext_vector_type(4))) float f32x4;
typedef __attribute__((ext_vector_type(2))) float f32x2;

__device__ __forceinline__ f32x4 mfma16(bf16x8 a, bf16x8 b, f32x4 c) {
    return __builtin_amdgcn_mfma_f32_16x16x32_bf16(a, b, c, 0, 0, 0);
}

__device__ __forceinline__ void gload16(const void* src, const char* ldsdst) {
    __builtin_amdgcn_global_load_lds(
        (const __attribute__((address_space(1))) void*)src,
        (__attribute__((address_space(3))) void*)ldsdst, 16, 0, 0);
}

__device__ __forceinline__ f32x2 sp(float x) { return (f32x2){x, x}; }

// K0 (fused): msg = E @ A via sparse index compaction, norms, bf16 casts,
// SoA q-tables qsoa[i][field][agent], and a degree-12 Chebyshev fit of
// f_i(g)=tanh(sc_i*exp(invT_i*g)) using ONLY float hardware transcendentals.
__global__ __launch_bounds__(256, 8) void prep_kernel(
    const float* __restrict__ E, const float* __restrict__ A,
    const float* __restrict__ persona,
    const float* __restrict__ Tt, const float* __restrict__ ee,
    const float* __restrict__ rr, const float* __restrict__ Ww,
    const int* __restrict__ times,
    __hip_bfloat16* __restrict__ Abf, __hip_bfloat16* __restrict__ Mbf,
    float* __restrict__ qsoa, float* __restrict__ cstg, int* __restrict__ ctr) {
    __shared__ int cnt;
    __shared__ int list[1024];
    const int a = blockIdx.x;
    const int t = threadIdx.x;
    if (t == 0) cnt = 0;
    __syncthreads();
    const float4* erow = (const float4*)(E + (size_t)a * N);
    for (int b = t; b < N / 4; b += 256) {
        const float4 v = erow[b];
        if (v.x != 0.f) list[atomicAdd(&cnt, 1)] = 4 * b;
        if (v.y != 0.f) list[atomicAdd(&cnt, 1)] = 4 * b + 1;
        if (v.z != 0.f) list[atomicAdd(&cnt, 1)] = 4 * b + 2;
        if (v.w != 0.f) list[atomicAdd(&cnt, 1)] = 4 * b + 3;
    }
    __syncthreads();
    const int c = cnt;
    float s0 = 0.f, s1 = 0.f, s2 = 0.f, s3 = 0.f;
    float s4 = 0.f, s5 = 0.f, s6 = 0.f, s7 = 0.f;
    int j = 0;
    for (; j + 8 <= c; j += 8) {
        s0 += A[(size_t)list[j] * F + t];
        s1 += A[(size_t)list[j + 1] * F + t];
        s2 += A[(size_t)list[j + 2] * F + t];
        s3 += A[(size_t)list[j + 3] * F + t];
        s4 += A[(size_t)list[j + 4] * F + t];
        s5 += A[(size_t)list[j + 5] * F + t];
        s6 += A[(size_t)list[j + 6] * F + t];
        s7 += A[(size_t)list[j + 7] * F + t];
    }
    for (; j < c; ++j) s0 += A[(size_t)list[j] * F + t];
    const float mv = ((s0 + s1) + (s2 + s3)) + ((s4 + s5) + (s6 + s7));
    const float av = A[(size_t)a * F + t];
    Abf[(size_t)a * F + t] = __float2bfloat16(av);
    Mbf[(size_t)a * F + t] = __float2bfloat16(mv);

    float paa = av * av, pam = av * mv, pmm = mv * mv;
    #pragma unroll
    for (int o = 32; o > 0; o >>= 1) {
        paa += __shfl_down(paa, o);
        pam += __shfl_down(pam, o);
        pmm += __shfl_down(pmm, o);
    }
    __shared__ float s[3][4];
    const int wid = t >> 6;
    if ((t & 63) == 0) { s[0][wid] = paa; s[1][wid] = pam; s[2][wid] = pmm; }
    __syncthreads();
    if (t < P) {
        const float naa = s[0][0] + s[0][1] + s[0][2] + s[0][3];
        const float nam = s[1][0] + s[1][1] + s[1][2] + s[1][3];
        const float nmm = s[2][0] + s[2][1] + s[2][2] + s[2][3];
        const float Ti = Tt[t], ei = ee[t], ri = rr[t], Wi = Ww[t];
        const float wb = (1.f - ri) * Wi;
        const float n2 = ri * ri * naa + 2.f * ri * wb * nam + wb * wb * nmm;
        const float rn = rsqrtf(n2);
        const float p = persona[(size_t)(*times) * (size_t)N * P + (size_t)a * P + t];
        qsoa[(t * 4 + 0) * N + a] = ri * rn;
        qsoa[(t * 4 + 1) * N + a] = wb * rn;
        qsoa[(t * 4 + 2) * N + a] = p;
        qsoa[(t * 4 + 3) * N + a] = p + (t == 0 ? 1.f : 0.f);
        if (a == 0) {
            const float kk = 1.f / (Ti + EPSV);
            const float scf = ei / (ei * __expf(kk) + EPSV);
            float ch[NC];
            #pragma unroll
            for (int j2 = 0; j2 < NC; ++j2) ch[j2] = 0.f;
            for (int m = 0; m < 32; ++m) {
                const float th = 3.14159265358979323846f * (m + 0.5f) / 32.f;
                const float c1 = __cosf(th);
                const float x = scf * __expf(kk * 1.05f * c1);
                const float e2 = __expf(2.f * x);
                const float fm = 1.f - 2.f / (e2 + 1.f);   // tanh(x)
                float cjm1 = 1.f, cj = c1;
                ch[0] += fm;
                ch[1] += fm * c1;
                #pragma unroll
                for (int j2 = 2; j2 < NC; ++j2) {
                    const float cn = 2.f * c1 * cj - cjm1;
                    ch[j2] += fm * cn;
                    cjm1 = cj;
                    cj = cn;
                }
            }
            #pragma unroll
            for (int j2 = 0; j2 < NC; ++j2) ch[j2] *= (j2 == 0 ? 1.f : 2.f) / 32.f;
            float mono[NC], Tp[NC], Tc[NC], Tn[NC];
            const float is = 1.f / 1.05f;
            #pragma unroll
            for (int k2 = 0; k2 < NC; ++k2) {
                mono[k2] = 0.f; Tp[k2] = 0.f; Tc[k2] = 0.f; Tn[k2] = 0.f;
            }
            Tp[0] = 1.f;
            Tc[1] = is;
            #pragma unroll
            for (int k2 = 0; k2 < NC; ++k2) mono[k2] += ch[0] * Tp[k2] + ch[1] * Tc[k2];
            for (int j2 = 2; j2 < NC; ++j2) {
                #pragma unroll
                for (int k2 = 0; k2 < NC; ++k2)
                    Tn[k2] = 2.f * is * (k2 ? Tc[k2 - 1] : 0.f) - Tp[k2];
                #pragma unroll
                for (int k2 = 0; k2 < NC; ++k2) mono[k2] += ch[j2] * Tn[k2];
                #pragma unroll
                for (int k2 = 0; k2 < NC; ++k2) { Tp[k2] = Tc[k2]; Tc[k2] = Tn[k2]; }
            }
            #pragma unroll
            for (int k2 = 0; k2 < NC; ++k2) cstg[t * NC + k2] = mono[k2];
        }
    }
    if (a == 0 && t == 0) *ctr = GRIDSZ;  // work-stealing counter (stream-ordered)
}

#define RAWBAR() do {                                   \
    __builtin_amdgcn_sched_barrier(0);                  \
    __builtin_amdgcn_s_barrier();                       \
    __builtin_amdgcn_sched_barrier(0);                  \
} while (0)

// K1: persistent fused 4-Gram MFMA + polynomial persona epilogue.
// Drain-free pipeline: rows from global (L2) into dbuf registers; cols-only
// LDS staging (3 buffers, stage-2-ahead); raw s_barrier + counted vmcnt --
// never vmcnt(0) in the loop, stores never drained at barriers.
__global__ __launch_bounds__(512) void gram_kernel(
    const __hip_bfloat16* __restrict__ Abf, const __hip_bfloat16* __restrict__ Mbf,
    const float* __restrict__ qsoa, const float* __restrict__ cstg,
    int* __restrict__ ctr, float* __restrict__ out) {
    // [0,24576): 3 bufs x (colA 4KB + colM 4KB)
    // [24576,29696): qrow SoA; [29696,34816): qcol SoA; [34816,35088): coeffs
    __shared__ __align__(16) char smem[35088];
    __shared__ int snext;

    const int t = threadIdx.x;
    const int lane = t & 63;
    const int w = t >> 6;          // 0..7
    const int wr = w >> 1;         // 0..3: 16-row strip
    const int wc = w & 1;          // 0..1: 32-col strip

    // staging: waves 0-3 stage colA rows (w&3)*16..+15, waves 4-7 colM.
    // 1 gload16/thread/step; source column pre-swizzled (slot^((row>>1)&3)).
    const int pA = w >> 2;
    const int sslot = (lane & 3) ^ ((lane >> 3) & 3);
    const int csrow = (w & 3) * 16 + (lane >> 2);
    const __hip_bfloat16* cmat = pA ? Mbf : Abf;
    const int ldsp = pA * 4096 + (w & 3) * 1024;

    // fragment-read geometry (matching swizzle)
    const int frow = lane & 15;
    const int fg = lane >> 4;
    const int jr = fg << 2;
    const int rdslot = (fg ^ ((frow >> 1) & 3)) << 4;
    const int coff0 = (wc * 32 + frow) * 64 + rdslot;
    const int coff1 = (wc * 32 + 16 + frow) * 64 + rdslot;

    const float* qlr = (const float*)(smem + 24576);
    const float* qlc = (const float*)(smem + 29696);
    const float* cfs = (const float*)(smem + 34816);

    int raw = blockIdx.x;
    while (raw < NTRI) {
        // XCD-chunked bijective swizzle (2080 % 8 == 0)
        const int bid = (raw & 7) * 260 + (raw >> 3);
        int bx = (int)((sqrtf(8.f * (float)bid + 1.f) - 1.f) * 0.5f);
        while ((bx + 1) * (bx + 2) / 2 <= bid) ++bx;
        while (bx * (bx + 1) / 2 > bid) --bx;
        const int by = bid - bx * (bx + 1) / 2;
        const int row0 = by << 6, col0 = bx << 6;

        const __hip_bfloat16* csrc =
            cmat + (size_t)(col0 + csrow) * F + sslot * 8;
        const __hip_bfloat16* prA =
            Abf + (size_t)(row0 + wr * 16 + frow) * F + fg * 8;
        const __hip_bfloat16* prM =
            Mbf + (size_t)(row0 + wr * 16 + frow) * F + fg * 8;

        #define STAGE(b, ks) gload16(csrc + (ks), smem + (b) * 8192 + ldsp)

        // barrier A: prev tile's buf1/iter-7 reads + epilogue q-reads complete
        RAWBAR();

        // prologue: stage steps 0,1; rows step 0; q tables; steal next tile
        STAGE(0, 0);
        STAGE(1, 32);
        bf16x8 rowA[2], rowM[2];
        rowA[0] = *(const bf16x8*)(prA);
        rowM[0] = *(const bf16x8*)(prM);
        if (w == 0) {
            #pragma unroll
            for (int it = 0; it < 5; ++it)
                gload16(qsoa + (it * 4 + (lane >> 4)) * N + row0 + (lane & 15) * 4,
                        smem + 24576 + it * 1024);
        } else if (w == 1) {
            #pragma unroll
            for (int it = 0; it < 5; ++it)
                gload16(qsoa + (it * 4 + (lane >> 4)) * N + col0 + (lane & 15) * 4,
                        smem + 29696 + it * 1024);
        } else if (w == 2) {
            if (lane < 17) gload16(cstg + lane * 4, smem + 34816);
        }
        if (t == 0) snext = atomicAdd(ctr, 1);
        // barrier B: own stage-0 retired (<=3 leaves stage1+rows0 in flight)
        asm volatile("s_waitcnt vmcnt(3)" ::: "memory");
        RAWBAR();

        f32x4 acc[4][2];  // [gram AA,AM,MA,MM][n]
        #pragma unroll
        for (int g = 0; g < 4; ++g)
            #pragma unroll
            for (int n = 0; n < 2; ++n) acc[g][n] = (f32x4){0.f, 0.f, 0.f, 0.f};

        #pragma unroll
        for (int s = 0; s < NSTEP; ++s) {
            if (s + 2 < NSTEP) STAGE((s + 2) % 3, (s + 2) * BK);
            if (s + 1 < NSTEP) {
                rowA[(s + 1) & 1] = *(const bf16x8*)(prA + (s + 1) * BK);
                rowM[(s + 1) & 1] = *(const bf16x8*)(prM + (s + 1) * BK);
            }
            const char* base = smem + (s % 3) * 8192;
            const bf16x8 bA0 = *(const bf16x8*)(base + coff0);
            const bf16x8 bA1 = *(const bf16x8*)(base + coff1);
            const bf16x8 bM0 = *(const bf16x8*)(base + 4096 + coff0);
            const bf16x8 bM1 = *(const bf16x8*)(base + 4096 + coff1);
            acc[0][0] = mfma16(rowA[s & 1], bA0, acc[0][0]);
            acc[0][1] = mfma16(rowA[s & 1], bA1, acc[0][1]);
            acc[1][0] = mfma16(rowA[s & 1], bM0, acc[1][0]);
            acc[1][1] = mfma16(rowA[s & 1], bM1, acc[1][1]);
            acc[2][0] = mfma16(rowM[s & 1], bA0, acc[2][0]);
            acc[2][1] = mfma16(rowM[s & 1], bA1, acc[2][1]);
            acc[3][0] = mfma16(rowM[s & 1], bM0, acc[3][0]);
            acc[3][1] = mfma16(rowM[s & 1], bM1, acc[3][1]);
            if (s + 1 < NSTEP) {
                // retire stage s+1 for all waves; leave {stage s+2, rows s+1}
                if (s + 2 < NSTEP) {
                    asm volatile("s_waitcnt vmcnt(3)" ::: "memory");
                } else {
                    asm volatile("s_waitcnt vmcnt(2)" ::: "memory");
                }
                RAWBAR();
            }
        }

        // Polynomial epilogue on float2 j-pairs (no transcendentals)
        f32x2 o1[2][2], o2[2][2];  // [n][jpair]
        #pragma unroll
        for (int n = 0; n < 2; ++n)
            #pragma unroll
            for (int jp = 0; jp < 2; ++jp) { o1[n][jp] = sp(0.f); o2[n][jp] = sp(0.f); }

        #pragma unroll
        for (int i = 0; i < P; ++i) {
            const int ib = i * 256;  // (i*4+field)*64
            float cf[NC];
            #pragma unroll
            for (int k = 0; k < NC; ++k) cf[k] = cfs[i * NC + k];
            float cA[2], cB[2], cP0[2], cP1[2];
            #pragma unroll
            for (int n = 0; n < 2; ++n) {
                const int cr = wc * 32 + n * 16 + frow;
                cA[n]  = qlc[ib + cr];
                cB[n]  = qlc[ib + 64 + cr];
                cP0[n] = qlc[ib + 128 + cr];
                cP1[n] = qlc[ib + 192 + cr];
            }
            #pragma unroll
            for (int jp = 0; jp < 2; ++jp) {
                const int rrw = wr * 16 + jr + jp * 2;
                const f32x2 rA  = *(const f32x2*)&qlr[ib + rrw];
                const f32x2 rB  = *(const f32x2*)&qlr[ib + 64 + rrw];
                const f32x2 rP0 = *(const f32x2*)&qlr[ib + 128 + rrw];
                const f32x2 rP1 = *(const f32x2*)&qlr[ib + 192 + rrw];
                #pragma unroll
                for (int n = 0; n < 2; ++n) {
                    const f32x2 aAA = (f32x2){acc[0][n][2 * jp], acc[0][n][2 * jp + 1]};
                    const f32x2 aAM = (f32x2){acc[1][n][2 * jp], acc[1][n][2 * jp + 1]};
                    const f32x2 aMA = (f32x2){acc[2][n][2 * jp], acc[2][n][2 * jp + 1]};
                    const f32x2 aMM = (f32x2){acc[3][n][2 * jp], acc[3][n][2 * jp + 1]};
                    const f32x2 h0 = rA * aAA + rB * aMA;
                    const f32x2 h1 = rA * aAM + rB * aMM;
                    const f32x2 g2 = h0 * sp(cA[n]) + h1 * sp(cB[n]);
                    f32x2 f2 = sp(cf[DDEG]);
                    #pragma unroll
                    for (int k = DDEG - 1; k >= 0; --k) f2 = f2 * g2 + sp(cf[k]);
                    o1[n][jp] += (f2 * rP1) * sp(cP0[n]);
                    o2[n][jp] += (f2 * rP0) * sp(cP1[n]);
                }
            }
        }

        // tile1 (row0, col0): coalesced stores
        #pragma unroll
        for (int jp = 0; jp < 2; ++jp)
            #pragma unroll
            for (int cc = 0; cc < 2; ++cc) {
                const int gr = row0 + wr * 16 + jr + jp * 2 + cc;
                #pragma unroll
                for (int n = 0; n < 2; ++n) {
                    const int gc = col0 + wc * 32 + n * 16 + frow;
                    out[(size_t)gr * N + gc] = o1[n][jp][cc];
                }
            }
        // tile2 (col0, row0): direct transposed scalar stores (L2 write-merged)
        if (by != bx) {
            #pragma unroll
            for (int jp = 0; jp < 2; ++jp)
                #pragma unroll
                for (int cc = 0; cc < 2; ++cc) {
                    const int gr = row0 + wr * 16 + jr + jp * 2 + cc;
                    #pragma unroll
                    for (int n = 0; n < 2; ++n) {
                        const int gc = col0 + wc * 32 + n * 16 + frow;
                        out[(size_t)gc * N + gr] = o2[n][jp][cc];
                    }
                }
        }
        raw = snext;  // written in prologue behind >=2 barriers since
        #undef STAGE
    }
}

extern "C" void kernel_launch(void* const* d_in, const int* in_sizes, int n_in,
                              void* d_out, int out_size, void* d_ws, size_t ws_size,
                              hipStream_t stream) {
    const float* A = (const float*)d_in[0];
    const float* E = (const float*)d_in[1];
    const float* persona = (const float*)d_in[2];
    const float* T = (const float*)d_in[3];
    const float* e = (const float*)d_in[4];
    const float* r = (const float*)d_in[5];
    const float* W = (const float*)d_in[6];
    const int* times = (const int*)d_in[7];
    float* out = (float*)d_out;

    char* ws = (char*)d_ws;
    __hip_bfloat16* Abf = (__hip_bfloat16*)ws;                    // 2 MB
    __hip_bfloat16* Mbf = (__hip_bfloat16*)(ws + (2 << 20));      // 2 MB
    float* qsoa = (float*)(ws + (4 << 20));                       // 320 KB SoA
    float* cstg = (float*)(ws + (4 << 20) + 5 * 4 * N * 4);       // 272 B coeffs
    int* ctr = (int*)(ws + (4 << 20) + 5 * 4 * N * 4 + 512);      // 4 B

    prep_kernel<<<N, 256, 0, stream>>>(E, A, persona, T, e, r, W, times,
                                       Abf, Mbf, qsoa, cstg, ctr);
    gram_kernel<<<GRIDSZ, 512, 0, stream>>>(Abf, Mbf, qsoa, cstg, ctr, out);
}

// Round 15
// 80.726 us; speedup vs baseline: 1.2473x; 1.2473x over previous
//
#include <hip/hip_runtime.h>
#include <hip/hip_bf16.h>

#define N 4096
#define F 256
#define P 5
#define EPSV 1e-8f
#define BK 32
#define NSTEP (F / BK)  // 8
#define NTRI 2080       // 64*65/2 upper-triangle 64x64 tiles
#define GRIDSZ 512      // persistent blocks (2/CU at 70KB LDS)
#define DDEG 12
#define NC (DDEG + 1)
#define PAN 16384       // bytes per panel buffer (4 panels x 4KB)
#define Q0OFF 49152     // q tables, 2 parities x 10240B
#define QSZ 10240
#define CFOFF 69632     // 272B poly coeffs

typedef __attribute__((ext_vector_type(8))) short bf16x8;
typedef __attribute__((ext_vector_type(4))) float f32x4;
typedef __attribute__((ext_vector_type(2))) float f32x2;

__device__ __forceinline__ f32x4 mfma16(bf16x8 a, bf16x8 b, f32x4 c) {
    return __builtin_amdgcn_mfma_f32_16x16x32_bf16(a, b, c, 0, 0, 0);
}

__device__ __forceinline__ void gload16(const void* src, const char* ldsdst) {
    __builtin_amdgcn_global_load_lds(
        (const __attribute__((address_space(1))) void*)src,
        (__attribute__((address_space(3))) void*)ldsdst, 16, 0, 0);
}

__device__ __forceinline__ f32x2 sp(float x) { return (f32x2){x, x}; }

#define SB() __builtin_amdgcn_sched_barrier(0)
#define RAWBAR() do { SB(); __builtin_amdgcn_s_barrier(); SB(); } while (0)

// K0 (fused): msg = E @ A sparse, norms, bf16 casts, SoA q-tables,
// degree-12 Chebyshev fit of f_i(g)=tanh(sc_i*exp(invT_i*g)) (float HW trans).
__global__ __launch_bounds__(256, 8) void prep_kernel(
    const float* __restrict__ E, const float* __restrict__ A,
    const float* __restrict__ persona,
    const float* __restrict__ Tt, const float* __restrict__ ee,
    const float* __restrict__ rr, const float* __restrict__ Ww,
    const int* __restrict__ times,
    __hip_bfloat16* __restrict__ Abf, __hip_bfloat16* __restrict__ Mbf,
    float* __restrict__ qsoa, float* __restrict__ cstg, int* __restrict__ ctr) {
    __shared__ int cnt;
    __shared__ int list[1024];
    const int a = blockIdx.x;
    const int t = threadIdx.x;
    if (t == 0) cnt = 0;
    __syncthreads();
    const float4* erow = (const float4*)(E + (size_t)a * N);
    for (int b = t; b < N / 4; b += 256) {
        const float4 v = erow[b];
        if (v.x != 0.f) list[atomicAdd(&cnt, 1)] = 4 * b;
        if (v.y != 0.f) list[atomicAdd(&cnt, 1)] = 4 * b + 1;
        if (v.z != 0.f) list[atomicAdd(&cnt, 1)] = 4 * b + 2;
        if (v.w != 0.f) list[atomicAdd(&cnt, 1)] = 4 * b + 3;
    }
    __syncthreads();
    const int c = cnt;
    float s0 = 0.f, s1 = 0.f, s2 = 0.f, s3 = 0.f;
    float s4 = 0.f, s5 = 0.f, s6 = 0.f, s7 = 0.f;
    int j = 0;
    for (; j + 8 <= c; j += 8) {
        s0 += A[(size_t)list[j] * F + t];
        s1 += A[(size_t)list[j + 1] * F + t];
        s2 += A[(size_t)list[j + 2] * F + t];
        s3 += A[(size_t)list[j + 3] * F + t];
        s4 += A[(size_t)list[j + 4] * F + t];
        s5 += A[(size_t)list[j + 5] * F + t];
        s6 += A[(size_t)list[j + 6] * F + t];
        s7 += A[(size_t)list[j + 7] * F + t];
    }
    for (; j < c; ++j) s0 += A[(size_t)list[j] * F + t];
    const float mv = ((s0 + s1) + (s2 + s3)) + ((s4 + s5) + (s6 + s7));
    const float av = A[(size_t)a * F + t];
    Abf[(size_t)a * F + t] = __float2bfloat16(av);
    Mbf[(size_t)a * F + t] = __float2bfloat16(mv);

    float paa = av * av, pam = av * mv, pmm = mv * mv;
    #pragma unroll
    for (int o = 32; o > 0; o >>= 1) {
        paa += __shfl_down(paa, o);
        pam += __shfl_down(pam, o);
        pmm += __shfl_down(pmm, o);
    }
    __shared__ float s[3][4];
    const int wid = t >> 6;
    if ((t & 63) == 0) { s[0][wid] = paa; s[1][wid] = pam; s[2][wid] = pmm; }
    __syncthreads();
    if (t < P) {
        const float naa = s[0][0] + s[0][1] + s[0][2] + s[0][3];
        const float nam = s[1][0] + s[1][1] + s[1][2] + s[1][3];
        const float nmm = s[2][0] + s[2][1] + s[2][2] + s[2][3];
        const float Ti = Tt[t], ei = ee[t], ri = rr[t], Wi = Ww[t];
        const float wb = (1.f - ri) * Wi;
        const float n2 = ri * ri * naa + 2.f * ri * wb * nam + wb * wb * nmm;
        const float rn = rsqrtf(n2);
        const float p = persona[(size_t)(*times) * (size_t)N * P + (size_t)a * P + t];
        qsoa[(t * 4 + 0) * N + a] = ri * rn;
        qsoa[(t * 4 + 1) * N + a] = wb * rn;
        qsoa[(t * 4 + 2) * N + a] = p;
        qsoa[(t * 4 + 3) * N + a] = p + (t == 0 ? 1.f : 0.f);
        if (a == 0) {
            const float kk = 1.f / (Ti + EPSV);
            const float scf = ei / (ei * __expf(kk) + EPSV);
            float ch[NC];
            #pragma unroll
            for (int j2 = 0; j2 < NC; ++j2) ch[j2] = 0.f;
            for (int m = 0; m < 32; ++m) {
                const float th = 3.14159265358979323846f * (m + 0.5f) / 32.f;
                const float c1 = __cosf(th);
                const float x = scf * __expf(kk * 1.05f * c1);
                const float e2 = __expf(2.f * x);
                const float fm = 1.f - 2.f / (e2 + 1.f);   // tanh(x)
                float cjm1 = 1.f, cj = c1;
                ch[0] += fm;
                ch[1] += fm * c1;
                #pragma unroll
                for (int j2 = 2; j2 < NC; ++j2) {
                    const float cn = 2.f * c1 * cj - cjm1;
                    ch[j2] += fm * cn;
                    cjm1 = cj;
                    cj = cn;
                }
            }
            #pragma unroll
            for (int j2 = 0; j2 < NC; ++j2) ch[j2] *= (j2 == 0 ? 1.f : 2.f) / 32.f;
            float mono[NC], Tp[NC], Tc[NC], Tn[NC];
            const float is = 1.f / 1.05f;
            #pragma unroll
            for (int k2 = 0; k2 < NC; ++k2) {
                mono[k2] = 0.f; Tp[k2] = 0.f; Tc[k2] = 0.f; Tn[k2] = 0.f;
            }
            Tp[0] = 1.f;
            Tc[1] = is;
            #pragma unroll
            for (int k2 = 0; k2 < NC; ++k2) mono[k2] += ch[0] * Tp[k2] + ch[1] * Tc[k2];
            for (int j2 = 2; j2 < NC; ++j2) {
                #pragma unroll
                for (int k2 = 0; k2 < NC; ++k2)
                    Tn[k2] = 2.f * is * (k2 ? Tc[k2 - 1] : 0.f) - Tp[k2];
                #pragma unroll
                for (int k2 = 0; k2 < NC; ++k2) mono[k2] += ch[j2] * Tn[k2];
                #pragma unroll
                for (int k2 = 0; k2 < NC; ++k2) { Tp[k2] = Tc[k2]; Tc[k2] = Tn[k2]; }
            }
            #pragma unroll
            for (int k2 = 0; k2 < NC; ++k2) cstg[t * NC + k2] = mono[k2];
        }
    }
    if (a == 0 && t == 0) *ctr = GRIDSZ;
}

// K1: persistent fused 4-Gram MFMA + poly epilogue. 3-buffer stage-2-ahead
// panels, counted vmcnt barriers, next-tile prologue hidden under epilogue.
__global__ __launch_bounds__(512) void gram_kernel(
    const __hip_bfloat16* __restrict__ Abf, const __hip_bfloat16* __restrict__ Mbf,
    const float* __restrict__ qsoa, const float* __restrict__ cstg,
    int* __restrict__ ctr, float* __restrict__ out) {
    // [0,49152): 3 bufs x 4 panels x [64][32] bf16
    // [49152,69632): q tables, 2 parities x {qrow 5KB, qcol 5KB}
    // [69632,69904): poly coeffs
    __shared__ __align__(16) char smem[69904];
    __shared__ int snext;

    const int t = threadIdx.x;
    const int lane = t & 63;
    const int w = t >> 6;
    const int wr = w >> 1;
    const int wc = w & 1;

    // staging geometry: wave w owns panel w>>1 (rowA,rowM,colA,colM), half w&1;
    // source column pre-swizzled (involution slot^((row>>1)&3)); LDS linear.
    const int sslot = (lane & 3) ^ ((lane >> 3) & 3);
    const int srowoff = (w & 1) * 32 + (lane >> 2);
    const int ldsp = (w >> 1) * 4096 + (w & 1) * 2048;
    const __hip_bfloat16* smat = ((w >> 1) & 1) ? Mbf : Abf;

    // fragment-read geometry (matching swizzle)
    const int frow = lane & 15;
    const int fg = lane >> 4;
    const int jr = fg << 2;
    const int rdslot = (fg ^ ((frow >> 1) & 3)) << 4;
    const int aoff = (wr * 16 + frow) * 64 + rdslot;
    const int coff0 = (wc * 32 + frow) * 64 + rdslot;
    const int coff1 = (wc * 32 + 16 + frow) * 64 + rdslot;
    const float* cfs = (const float*)(smem + CFOFF);

    #define DECODE(id, oby, obx) do {                                     \
        const int bid_ = ((id) & 7) * 260 + ((id) >> 3);                  \
        int bx_ = (int)((sqrtf(8.f * (float)bid_ + 1.f) - 1.f) * 0.5f);   \
        while ((bx_ + 1) * (bx_ + 2) / 2 <= bid_) ++bx_;                  \
        while (bx_ * (bx_ + 1) / 2 > bid_) --bx_;                         \
        (obx) = bx_;                                                      \
        (oby) = bid_ - bx_ * (bx_ + 1) / 2;                               \
    } while (0)

    // prologue for a tile: stage K-steps 0,1 into bufs 0,1 + q tables (parity)
    #define PROLOGUE(r0_, c0_, qp_) do {                                  \
        const int sb_ = (w < 4) ? (r0_) : (c0_);                          \
        const __hip_bfloat16* ps_ =                                       \
            smat + (size_t)(sb_ + srowoff) * F + sslot * 8;               \
        gload16(ps_, smem + ldsp);                                        \
        gload16(ps_ + 16 * F, smem + ldsp + 1024);                        \
        gload16(ps_ + 32, smem + PAN + ldsp);                             \
        gload16(ps_ + 32 + 16 * F, smem + PAN + ldsp + 1024);             \
        const int qb_ = Q0OFF + (qp_) * QSZ;                              \
        if (w == 0) {                                                     \
            _Pragma("unroll")                                             \
            for (int it = 0; it < 5; ++it)                                \
                gload16(qsoa + (it * 4 + (lane >> 4)) * N + (r0_) +       \
                        (lane & 15) * 4, smem + qb_ + it * 1024);         \
        } else if (w == 1) {                                              \
            _Pragma("unroll")                                             \
            for (int it = 0; it < 5; ++it)                                \
                gload16(qsoa + (it * 4 + (lane >> 4)) * N + (c0_) +       \
                        (lane & 15) * 4, smem + qb_ + 5120 + it * 1024);  \
        }                                                                 \
        if (t == 0) snext = atomicAdd(ctr, 1);                            \
    } while (0)

    int raw = blockIdx.x;
    int by, bx;
    DECODE(raw, by, bx);
    int row0 = by << 6, col0 = bx << 6;
    int qpar = 0;
    int pend = 0;  // stores outstanding from previous tile (0/8/16)

    // initial prologue (+ one-time coeff load)
    PROLOGUE(row0, col0, 0);
    if (w == 2 && lane < 17) gload16(cstg + lane * 4, smem + CFOFF);

    for (;;) {
        // tile-top barrier: counted wait = exactly the store count, so the
        // (older) prologue loads are proven retired without draining stores.
        if (pend == 16) asm volatile("s_waitcnt vmcnt(16)" ::: "memory");
        else if (pend == 8) asm volatile("s_waitcnt vmcnt(8)" ::: "memory");
        else asm volatile("s_waitcnt vmcnt(0)" ::: "memory");
        RAWBAR();

        const int nxt = snext;  // written in prologue, behind the barrier

        const int sbc = (w < 4) ? row0 : col0;
        const __hip_bfloat16* psrc =
            smat + (size_t)(sbc + srowoff) * F + sslot * 8;

        f32x4 acc[4][2];
        #pragma unroll
        for (int g = 0; g < 4; ++g)
            #pragma unroll
            for (int n = 0; n < 2; ++n) acc[g][n] = (f32x4){0.f, 0.f, 0.f, 0.f};

        #pragma unroll
        for (int s = 0; s < NSTEP; ++s) {
            if (s + 2 < NSTEP) {  // stage-2-ahead into buf (s+2)%3
                const char* lb = smem + ((s + 2) % 3) * PAN + ldsp;
                gload16(psrc + (s + 2) * BK, lb);
                gload16(psrc + (s + 2) * BK + 16 * F, lb + 1024);
            }
            const char* base = smem + (s % 3) * PAN;
            const bf16x8 aA = *(const bf16x8*)(base + aoff);
            const bf16x8 aM = *(const bf16x8*)(base + 4096 + aoff);
            const bf16x8 bA0 = *(const bf16x8*)(base + 8192 + coff0);
            const bf16x8 bA1 = *(const bf16x8*)(base + 8192 + coff1);
            const bf16x8 bM0 = *(const bf16x8*)(base + 12288 + coff0);
            const bf16x8 bM1 = *(const bf16x8*)(base + 12288 + coff1);
            acc[0][0] = mfma16(aA, bA0, acc[0][0]);
            acc[0][1] = mfma16(aA, bA1, acc[0][1]);
            acc[1][0] = mfma16(aA, bM0, acc[1][0]);
            acc[1][1] = mfma16(aA, bM1, acc[1][1]);
            acc[2][0] = mfma16(aM, bA0, acc[2][0]);
            acc[2][1] = mfma16(aM, bA1, acc[2][1]);
            acc[3][0] = mfma16(aM, bM0, acc[3][0]);
            acc[3][1] = mfma16(aM, bM1, acc[3][1]);
            if (s + 1 < NSTEP) {
                // need stage s+1 landed; newest own ops = stage s+2 (2 loads)
                if (s + 2 < NSTEP) asm volatile("s_waitcnt vmcnt(2)" ::: "memory");
                else asm volatile("s_waitcnt vmcnt(0)" ::: "memory");
                RAWBAR();
            }
        }

        // post-K barrier: all waves' panel reads consumed (MFMA deps) -> bufs
        // 0,1 and the other q parity are safe to overwrite.
        RAWBAR();

        const bool have = (nxt < NTRI);
        int nby = 0, nbx = 0, nrow0 = 0, ncol0 = 0;
        if (have) {
            DECODE(nxt, nby, nbx);
            nrow0 = nby << 6;
            ncol0 = nbx << 6;
            PROLOGUE(nrow0, ncol0, qpar ^ 1);  // latency hides under epilogue
        }

        // Polynomial epilogue (reads q parity qpar)
        const float* qlr = (const float*)(smem + Q0OFF + qpar * QSZ);
        const float* qlc = qlr + 1280;
        f32x2 o1[2][2], o2[2][2];
        #pragma unroll
        for (int n = 0; n < 2; ++n)
            #pragma unroll
            for (int jp = 0; jp < 2; ++jp) { o1[n][jp] = sp(0.f); o2[n][jp] = sp(0.f); }

        #pragma unroll
        for (int i = 0; i < P; ++i) {
            const int ib = i * 256;
            float cf[NC];
            #pragma unroll
            for (int k = 0; k < NC; ++k) cf[k] = cfs[i * NC + k];
            float cA[2], cB[2], cP0[2], cP1[2];
            #pragma unroll
            for (int n = 0; n < 2; ++n) {
                const int cr = wc * 32 + n * 16 + frow;
                cA[n]  = qlc[ib + cr];
                cB[n]  = qlc[ib + 64 + cr];
                cP0[n] = qlc[ib + 128 + cr];
                cP1[n] = qlc[ib + 192 + cr];
            }
            #pragma unroll
            for (int jp = 0; jp < 2; ++jp) {
                const int rrw = wr * 16 + jr + jp * 2;
                const f32x2 rA  = *(const f32x2*)&qlr[ib + rrw];
                const f32x2 rB  = *(const f32x2*)&qlr[ib + 64 + rrw];
                const f32x2 rP0 = *(const f32x2*)&qlr[ib + 128 + rrw];
                const f32x2 rP1 = *(const f32x2*)&qlr[ib + 192 + rrw];
                #pragma unroll
                for (int n = 0; n < 2; ++n) {
                    const f32x2 aAA = (f32x2){acc[0][n][2 * jp], acc[0][n][2 * jp + 1]};
                    const f32x2 aAM = (f32x2){acc[1][n][2 * jp], acc[1][n][2 * jp + 1]};
                    const f32x2 aMA = (f32x2){acc[2][n][2 * jp], acc[2][n][2 * jp + 1]};
                    const f32x2 aMM = (f32x2){acc[3][n][2 * jp], acc[3][n][2 * jp + 1]};
                    const f32x2 h0 = rA * aAA + rB * aMA;
                    const f32x2 h1 = rA * aAM + rB * aMM;
                    const f32x2 g2 = h0 * sp(cA[n]) + h1 * sp(cB[n]);
                    f32x2 f2 = sp(cf[DDEG]);
                    #pragma unroll
                    for (int k = DDEG - 1; k >= 0; --k) f2 = f2 * g2 + sp(cf[k]);
                    o1[n][jp] += (f2 * rP1) * sp(cP0[n]);
                    o2[n][jp] += (f2 * rP0) * sp(cP1[n]);
                }
            }
        }

        // stores (issued AFTER prologue loads -> they are the newest vmem ops)
        #pragma unroll
        for (int jp = 0; jp < 2; ++jp)
            #pragma unroll
            for (int cc = 0; cc < 2; ++cc) {
                const int gr = row0 + wr * 16 + jr + jp * 2 + cc;
                #pragma unroll
                for (int n = 0; n < 2; ++n) {
                    const int gc = col0 + wc * 32 + n * 16 + frow;
                    out[(size_t)gr * N + gc] = o1[n][jp][cc];
                }
            }
        if (by != bx) {
            #pragma unroll
            for (int jp = 0; jp < 2; ++jp)
                #pragma unroll
                for (int cc = 0; cc < 2; ++cc) {
                    const int gr = row0 + wr * 16 + jr + jp * 2 + cc;
                    #pragma unroll
                    for (int n = 0; n < 2; ++n) {
                        const int gc = col0 + wc * 32 + n * 16 + frow;
                        out[(size_t)gc * N + gr] = o2[n][jp][cc];
                    }
                }
            pend = 16;
        } else {
            pend = 8;
        }

        if (!have) break;
        raw = nxt; by = nby; bx = nbx; row0 = nrow0; col0 = ncol0; qpar ^= 1;
    }
    #undef PROLOGUE
    #undef DECODE
}

extern "C" void kernel_launch(void* const* d_in, const int* in_sizes, int n_in,
                              void* d_out, int out_size, void* d_ws, size_t ws_size,
                              hipStream_t stream) {
    const float* A = (const float*)d_in[0];
    const float* E = (const float*)d_in[1];
    const float* persona = (const float*)d_in[2];
    const float* T = (const float*)d_in[3];
    const float* e = (const float*)d_in[4];
    const float* r = (const float*)d_in[5];
    const float* W = (const float*)d_in[6];
    const int* times = (const int*)d_in[7];
    float* out = (float*)d_out;

    char* ws = (char*)d_ws;
    __hip_bfloat16* Abf = (__hip_bfloat16*)ws;                    // 2 MB
    __hip_bfloat16* Mbf = (__hip_bfloat16*)(ws + (2 << 20));      // 2 MB
    float* qsoa = (float*)(ws + (4 << 20));                       // 320 KB SoA
    float* cstg = (float*)(ws + (4 << 20) + 5 * 4 * N * 4);       // 272 B coeffs
    int* ctr = (int*)(ws + (4 << 20) + 5 * 4 * N * 4 + 512);      // 4 B

    prep_kernel<<<N, 256, 0, stream>>>(E, A, persona, T, e, r, W, times,
                                       Abf, Mbf, qsoa, cstg, ctr);
    gram_kernel<<<GRIDSZ, 512, 0, stream>>>(Abf, Mbf, qsoa, cstg, ctr, out);
}